// Round 5
// baseline (77.705 us; speedup 1.0000x reference)
//
#include <hip/hip_runtime.h>
#include <hip/hip_fp16.h>

#define HH 64
#define WW 96
#define DD 64
#define VV 4
#define CC 16
#define HW (HH*WW)
#define EPSF 1e-8f
#define DPT 2   // depth planes per thread

typedef _Float16 half2_t __attribute__((ext_vector_type(2)));

#if defined(__has_builtin)
#if __has_builtin(__builtin_amdgcn_fdot2)
#define HAVE_FDOT2 1
#endif
#endif

__device__ __forceinline__ float fdot2_acc(half2_t a, half2_t b, float c) {
#ifdef HAVE_FDOT2
    return __builtin_amdgcn_fdot2(a, b, c, false);
#else
    return c + (float)a.x * (float)b.x + (float)a.y * (float)b.y;
#endif
}

// ---------------------------------------------------------------------------
// Pack kernel: src (V,C,HW) fp32 -> srcT (V,HW,C) fp16
//              cur (C,HW)  fp32 -> curT (HW,C)   fp16
// ---------------------------------------------------------------------------
__global__ __launch_bounds__(256) void cv_pack_kernel(
    const float* __restrict__ src, const float* __restrict__ cur,
    __half* __restrict__ srcT, __half* __restrict__ curT)
{
    int tid = blockIdx.x * blockDim.x + threadIdx.x;
    if (tid < VV * HW) {
        int v  = tid / HW;
        int hw = tid - v * HW;
        unsigned short pk[CC];
        #pragma unroll
        for (int c = 0; c < CC; ++c) {
            float f = src[(size_t)v * CC * HW + c * HW + hw];
            pk[c] = __half_as_ushort(__float2half(f));
        }
        uint4* dst = (uint4*)(srcT + (size_t)tid * CC);
        dst[0] = *(uint4*)&pk[0];
        dst[1] = *(uint4*)&pk[8];
    } else {
        int hw = tid - VV * HW;
        if (hw < HW) {
            unsigned short pk[CC];
            #pragma unroll
            for (int c = 0; c < CC; ++c) {
                float f = cur[c * HW + hw];
                pk[c] = __half_as_ushort(__float2half(f));
            }
            uint4* dst = (uint4*)(curT + (size_t)hw * CC);
            dst[0] = *(uint4*)&pk[0];
            dst[1] = *(uint4*)&pk[8];
        }
    }
}

// ---------------------------------------------------------------------------
// Main fused kernel: projection + bilinear + channel-dot + view sum.
// One thread per (depth-pair, h, w): DPT depth planes share cf2/ray/P-hoist.
// ---------------------------------------------------------------------------
__global__ __launch_bounds__(256) void cost_volume_f16_kernel(
    const __half* __restrict__ curT,   // (HW,C) fp16
    const __half* __restrict__ srcT,   // (V,HW,C) fp16
    const float* __restrict__ extr,    // (V,4,4)
    const float* __restrict__ Ks,      // (V,4,4)
    const float* __restrict__ invK,    // (4,4)
    const float* __restrict__ min_d,
    const float* __restrict__ max_d,
    float* __restrict__ out)           // (D,HW)
{
    __shared__ __align__(16) float P_s[VV * 12];
    {
        int t = threadIdx.x;
        if (t < VV * 12) {
            int v   = t / 12;
            int r   = (t % 12) / 4;
            int col = t % 4;
            float s = 0.f;
            #pragma unroll
            for (int k = 0; k < 4; ++k)
                s += Ks[v * 16 + r * 4 + k] * extr[v * 16 + k * 4 + col];
            P_s[t] = s;
        }
    }
    __syncthreads();

    int tid = blockIdx.x * blockDim.x + threadIdx.x;
    if (tid >= (DD / DPT) * HW) return;
    int dp = tid / HW;          // depth-pair index
    int hw = tid - dp * HW;
    int h  = hw / WW;
    int w  = hw - h * WW;
    int d0 = dp * DPT;

    float px = (float)w + 0.5f, py = (float)h + 0.5f;
    float rx = invK[0] * px + invK[1] * py + invK[2];
    float ry = invK[4] * px + invK[5] * py + invK[6];
    float rz = invK[8] * px + invK[9] * py + invK[10];

    float inv_min = 1.f / min_d[0];
    float inv_max = 1.f / max_d[0];

    half2_t cf2[8];
    {
        const uint4* p = (const uint4*)(curT + (size_t)hw * CC);
        *(uint4*)&cf2[0] = p[0];
        *(uint4*)&cf2[4] = p[1];
    }

    // Hoist P into per-thread affine constants: c{x,y,z} = depth*A + B
    float Ax[VV], Bx[VV], Ay[VV], By[VV], Az[VV], Bz[VV];
    #pragma unroll
    for (int v = 0; v < VV; ++v) {
        const float4* Pv = (const float4*)&P_s[v * 12];
        float4 prx = Pv[0], pry = Pv[1], prz = Pv[2];   // 3x ds_read_b128
        Ax[v] = prx.x * rx + prx.y * ry + prx.z * rz;  Bx[v] = prx.w;
        Ay[v] = pry.x * rx + pry.y * ry + pry.z * rz;  By[v] = pry.w;
        Az[v] = prz.x * rx + prz.y * ry + prz.z * rz;  Bz[v] = prz.w;
    }

    #pragma unroll
    for (int j = 0; j < DPT; ++j) {
        int d = d0 + j;
        float depth = 1.f / (inv_min + (inv_max - inv_min) * ((float)d / (float)(DD - 1)));

        float acc = 0.f;
        #pragma unroll
        for (int v = 0; v < VV; ++v) {
            float cx = fmaf(depth, Ax[v], Bx[v]);
            float cy = fmaf(depth, Ay[v], By[v]);
            float cz = fmaf(depth, Az[v], Bz[v]);
            float iz = 1.f / (cz + EPSF);
            float x = cx * iz - 0.5f;
            float y = cy * iz - 0.5f;
            float x0f = floorf(x), y0f = floorf(y);
            float fx = x - x0f, fy = y - y0f;
            float x1f = x0f + 1.f, y1f = y0f + 1.f;
            int ix0 = (int)fminf(fmaxf(x0f, 0.f), (float)(WW - 1));
            int ix1 = (int)fminf(fmaxf(x1f, 0.f), (float)(WW - 1));
            int iy0 = (int)fminf(fmaxf(y0f, 0.f), (float)(HH - 1));
            int iy1 = (int)fminf(fmaxf(y1f, 0.f), (float)(HH - 1));
            float m   = (cz > 0.f) ? 1.f : 0.f;
            float mx0 = ((x0f >= 0.f) && (x0f < (float)WW)) ? m : 0.f;
            float mx1 = ((x1f >= 0.f) && (x1f < (float)WW)) ? m : 0.f;
            float my0 = ((y0f >= 0.f) && (y0f < (float)HH)) ? 1.f : 0.f;
            float my1 = ((y1f >= 0.f) && (y1f < (float)HH)) ? 1.f : 0.f;
            float w00 = (1.f - fx) * (1.f - fy) * mx0 * my0;
            float w01 = fx * (1.f - fy) * mx1 * my0;
            float w10 = (1.f - fx) * fy * mx0 * my1;
            float w11 = fx * fy * mx1 * my1;

            const __half* base = srcT + (size_t)v * HW * CC;
            uint4 buf[8];
            {
                const uint4* t00 = (const uint4*)(base + (size_t)(iy0 * WW + ix0) * CC);
                const uint4* t01 = (const uint4*)(base + (size_t)(iy0 * WW + ix1) * CC);
                const uint4* t10 = (const uint4*)(base + (size_t)(iy1 * WW + ix0) * CC);
                const uint4* t11 = (const uint4*)(base + (size_t)(iy1 * WW + ix1) * CC);
                buf[0] = t00[0]; buf[1] = t00[1];
                buf[2] = t01[0]; buf[3] = t01[1];
                buf[4] = t10[0]; buf[5] = t10[1];
                buf[6] = t11[0]; buf[7] = t11[1];
            }
            const half2_t* hv = (const half2_t*)buf;
            float wgt[4] = {w00, w01, w10, w11};
            #pragma unroll
            for (int t = 0; t < 4; ++t) {
                float dtap = 0.f;
                #pragma unroll
                for (int i = 0; i < 8; ++i)
                    dtap = fdot2_acc(hv[8 * t + i], cf2[i], dtap);
                acc = fmaf(wgt[t], dtap, acc);
            }
        }
        out[(size_t)d * HW + hw] = acc;
    }
}

// ---------------------------------------------------------------------------
// Fallback (no workspace): original-layout fp32 gather.
// ---------------------------------------------------------------------------
__global__ __launch_bounds__(256) void cost_volume_fallback_kernel(
    const float* __restrict__ curF,   // (C,HW)
    const float* __restrict__ srcF,   // (V,C,HW)
    const float* __restrict__ extr,
    const float* __restrict__ Ks,
    const float* __restrict__ invK,
    const float* __restrict__ min_d,
    const float* __restrict__ max_d,
    float* __restrict__ out)
{
    __shared__ float P_s[VV * 12];
    {
        int t = threadIdx.x;
        if (t < VV * 12) {
            int v   = t / 12;
            int r   = (t % 12) / 4;
            int col = t % 4;
            float s = 0.f;
            #pragma unroll
            for (int k = 0; k < 4; ++k)
                s += Ks[v * 16 + r * 4 + k] * extr[v * 16 + k * 4 + col];
            P_s[t] = s;
        }
    }
    __syncthreads();

    int tid = blockIdx.x * blockDim.x + threadIdx.x;
    if (tid >= DD * HW) return;
    int d  = tid / HW;
    int hw = tid - d * HW;
    int h  = hw / WW;
    int w  = hw - h * WW;

    float px = (float)w + 0.5f, py = (float)h + 0.5f;
    float rx = invK[0] * px + invK[1] * py + invK[2];
    float ry = invK[4] * px + invK[5] * py + invK[6];
    float rz = invK[8] * px + invK[9] * py + invK[10];

    float inv_min = 1.f / min_d[0];
    float inv_max = 1.f / max_d[0];
    float depth   = 1.f / (inv_min + (inv_max - inv_min) * ((float)d / (float)(DD - 1)));

    float cf[CC];
    #pragma unroll
    for (int c = 0; c < CC; ++c) cf[c] = curF[c * HW + hw];

    float acc = 0.f;
    #pragma unroll
    for (int v = 0; v < VV; ++v) {
        const float* P = &P_s[v * 12];
        float cx = depth * (P[0] * rx + P[1] * ry + P[2]  * rz) + P[3];
        float cy = depth * (P[4] * rx + P[5] * ry + P[6]  * rz) + P[7];
        float cz = depth * (P[8] * rx + P[9] * ry + P[10] * rz) + P[11];
        if (cz > 0.f) {
            float iz = 1.f / (cz + EPSF);
            float x = cx * iz - 0.5f;
            float y = cy * iz - 0.5f;
            float x0f = floorf(x), y0f = floorf(y);
            float fx = x - x0f, fy = y - y0f;
            float x1f = x0f + 1.f, y1f = y0f + 1.f;
            int ix0 = (int)fminf(fmaxf(x0f, 0.f), (float)(WW - 1));
            int ix1 = (int)fminf(fmaxf(x1f, 0.f), (float)(WW - 1));
            int iy0 = (int)fminf(fmaxf(y0f, 0.f), (float)(HH - 1));
            int iy1 = (int)fminf(fmaxf(y1f, 0.f), (float)(HH - 1));
            bool vx0 = (x0f >= 0.f) && (x0f < (float)WW);
            bool vx1 = (x1f >= 0.f) && (x1f < (float)WW);
            bool vy0 = (y0f >= 0.f) && (y0f < (float)HH);
            bool vy1 = (y1f >= 0.f) && (y1f < (float)HH);
            float w00 = (vx0 && vy0) ? (1.f - fx) * (1.f - fy) : 0.f;
            float w01 = (vx1 && vy0) ? fx * (1.f - fy) : 0.f;
            float w10 = (vx0 && vy1) ? (1.f - fx) * fy : 0.f;
            float w11 = (vx1 && vy1) ? fx * fy : 0.f;

            float d00 = 0.f, d01 = 0.f, d10 = 0.f, d11 = 0.f;
            int b = v * CC * HW;
            int i00 = iy0 * WW + ix0, i01 = iy0 * WW + ix1;
            int i10 = iy1 * WW + ix0, i11 = iy1 * WW + ix1;
            #pragma unroll
            for (int c = 0; c < CC; ++c) {
                const float* fc = srcF + b + c * HW;
                d00 += fc[i00] * cf[c];
                d01 += fc[i01] * cf[c];
                d10 += fc[i10] * cf[c];
                d11 += fc[i11] * cf[c];
            }
            acc += w00 * d00 + w01 * d01 + w10 * d10 + w11 * d11;
        }
    }
    out[tid] = acc;
}

extern "C" void kernel_launch(void* const* d_in, const int* in_sizes, int n_in,
                              void* d_out, int out_size, void* d_ws, size_t ws_size,
                              hipStream_t stream) {
    const float* cur  = (const float*)d_in[0];
    const float* src  = (const float*)d_in[1];
    const float* extr = (const float*)d_in[2];
    const float* Ks   = (const float*)d_in[3];
    const float* invK = (const float*)d_in[4];
    const float* mind = (const float*)d_in[5];
    const float* maxd = (const float*)d_in[6];
    float* out = (float*)d_out;

    const size_t need = (size_t)(VV * HW * CC + HW * CC) * sizeof(__half);

    if (ws_size >= need) {
        __half* srcT = (__half*)d_ws;
        __half* curT = srcT + (size_t)VV * HW * CC;
        const int total = VV * HW + HW;
        cv_pack_kernel<<<(total + 255) / 256, 256, 0, stream>>>(src, cur, srcT, curT);
        const int n_thr = (DD / DPT) * HW;
        cost_volume_f16_kernel<<<(n_thr + 255) / 256, 256, 0, stream>>>(
            curT, srcT, extr, Ks, invK, mind, maxd, out);
    } else {
        const int n_out = DD * HW;
        cost_volume_fallback_kernel<<<(n_out + 255) / 256, 256, 0, stream>>>(
            cur, src, extr, Ks, invK, mind, maxd, out);
    }
}

// Round 7
// 76.496 us; speedup vs baseline: 1.0158x; 1.0158x over previous
//
#include <hip/hip_runtime.h>
#include <hip/hip_fp16.h>

#define HH 64
#define WW 96
#define DD 64
#define VV 4
#define CC 16
#define HW (HH*WW)
#define EPSF 1e-8f

typedef _Float16 half2_t __attribute__((ext_vector_type(2)));
typedef __fp16  pkhalf2_t __attribute__((ext_vector_type(2)));   // cvt_pkrtz native type

#if defined(__has_builtin)
#if __has_builtin(__builtin_amdgcn_fdot2)
#define HAVE_FDOT2 1
#endif
#endif

__device__ __forceinline__ float fdot2_acc(half2_t a, half2_t b, float c) {
#ifdef HAVE_FDOT2
    return __builtin_amdgcn_fdot2(a, b, c, false);
#else
    return c + (float)a.x * (float)b.x + (float)a.y * (float)b.y;
#endif
}

// v_cvt_pkrtz_f16_f32 -> 32-bit payload of two f16
__device__ __forceinline__ unsigned int pk2(float a, float b) {
    pkhalf2_t p = __builtin_amdgcn_cvt_pkrtz(a, b);
    return __builtin_bit_cast(unsigned int, p);
}

// v_rcp_f32: 1 instruction, ~1 ulp — plenty for bf16-grade tolerance
__device__ __forceinline__ float fast_rcp(float x) {
    return __builtin_amdgcn_rcpf(x);
}

// ---------------------------------------------------------------------------
// Pack kernel: src (V,C,HW) fp32 -> srcT (V,HW,C) fp16
//              cur (C,HW)  fp32 -> curT (HW,C)   fp16
// ---------------------------------------------------------------------------
__global__ __launch_bounds__(256) void cv_pack_kernel(
    const float* __restrict__ src, const float* __restrict__ cur,
    __half* __restrict__ srcT, __half* __restrict__ curT)
{
    int tid = blockIdx.x * blockDim.x + threadIdx.x;
    if (tid < VV * HW) {
        int v  = tid / HW;
        int hw = tid - v * HW;
        unsigned int pk[8];
        const float* b = src + (size_t)v * CC * HW + hw;
        #pragma unroll
        for (int i = 0; i < 8; ++i)
            pk[i] = pk2(b[(2*i) * HW], b[(2*i+1) * HW]);
        uint4* dst = (uint4*)(srcT + (size_t)tid * CC);
        dst[0] = *(uint4*)&pk[0];
        dst[1] = *(uint4*)&pk[4];
    } else {
        int hw = tid - VV * HW;
        if (hw < HW) {
            unsigned int pk[8];
            const float* b = cur + hw;
            #pragma unroll
            for (int i = 0; i < 8; ++i)
                pk[i] = pk2(b[(2*i) * HW], b[(2*i+1) * HW]);
            uint4* dst = (uint4*)(curT + (size_t)hw * CC);
            dst[0] = *(uint4*)&pk[0];
            dst[1] = *(uint4*)&pk[4];
        }
    }
}

// 32B fp16 tap: 8 x v_dot2_f32_f16 against fp16 cf, fp32 accumulate
__device__ __forceinline__ float tap_dot16(const __half* __restrict__ p,
                                           const half2_t* __restrict__ cf2)
{
    half2_t hv[8];
    const uint4* q = (const uint4*)p;
    *(uint4*)&hv[0] = q[0];
    *(uint4*)&hv[4] = q[1];
    float s = 0.f;
    #pragma unroll
    for (int i = 0; i < 8; ++i)
        s = fdot2_acc(hv[i], cf2[i], s);
    return s;
}

// ---------------------------------------------------------------------------
// Main fused kernel — R3 structure (best measured), divisions -> v_rcp_f32.
// One thread per output element (d, h, w).
// ---------------------------------------------------------------------------
__global__ __launch_bounds__(256) void cost_volume_f16_kernel(
    const __half* __restrict__ curT,
    const __half* __restrict__ srcT,
    const float* __restrict__ extr,   // (V,4,4)
    const float* __restrict__ Ks,     // (V,4,4)
    const float* __restrict__ invK,   // (4,4)
    const float* __restrict__ min_d,
    const float* __restrict__ max_d,
    float* __restrict__ out)          // (D,HW)
{
    __shared__ __align__(16) float P_s[VV * 12];
    {
        int t = threadIdx.x;
        if (t < VV * 12) {
            int v   = t / 12;
            int r   = (t % 12) / 4;
            int col = t % 4;
            float s = 0.f;
            #pragma unroll
            for (int k = 0; k < 4; ++k)
                s += Ks[v * 16 + r * 4 + k] * extr[v * 16 + k * 4 + col];
            P_s[t] = s;
        }
    }
    __syncthreads();

    int tid = blockIdx.x * blockDim.x + threadIdx.x;
    if (tid >= DD * HW) return;
    int d  = tid / HW;
    int hw = tid - d * HW;
    int h  = hw / WW;
    int w  = hw - h * WW;

    float px = (float)w + 0.5f, py = (float)h + 0.5f;
    float rx = invK[0] * px + invK[1] * py + invK[2];
    float ry = invK[4] * px + invK[5] * py + invK[6];
    float rz = invK[8] * px + invK[9] * py + invK[10];

    float inv_min = fast_rcp(min_d[0]);
    float inv_max = fast_rcp(max_d[0]);
    float depth   = fast_rcp(fmaf((inv_max - inv_min), (float)d * (1.f / (float)(DD - 1)), inv_min));

    half2_t cf2[8];
    {
        const uint4* p = (const uint4*)(curT + (size_t)hw * CC);
        *(uint4*)&cf2[0] = p[0];
        *(uint4*)&cf2[4] = p[1];
    }

    float acc = 0.f;
    #pragma unroll
    for (int v = 0; v < VV; ++v) {
        const float4* Pv = (const float4*)&P_s[v * 12];
        float4 prx = Pv[0], pry = Pv[1], prz = Pv[2];   // 3x ds_read_b128
        float cx = depth * (prx.x * rx + prx.y * ry + prx.z * rz) + prx.w;
        float cy = depth * (pry.x * rx + pry.y * ry + pry.z * rz) + pry.w;
        float cz = depth * (prz.x * rx + prz.y * ry + prz.z * rz) + prz.w;
        if (cz > 0.f) {
            float iz = fast_rcp(cz + EPSF);
            float x = cx * iz - 0.5f;
            float y = cy * iz - 0.5f;
            float x0f = floorf(x), y0f = floorf(y);
            float fx = x - x0f, fy = y - y0f;
            float x1f = x0f + 1.f, y1f = y0f + 1.f;
            int ix0 = (int)fminf(fmaxf(x0f, 0.f), (float)(WW - 1));
            int ix1 = (int)fminf(fmaxf(x1f, 0.f), (float)(WW - 1));
            int iy0 = (int)fminf(fmaxf(y0f, 0.f), (float)(HH - 1));
            int iy1 = (int)fminf(fmaxf(y1f, 0.f), (float)(HH - 1));
            bool vx0 = (x0f >= 0.f) && (x0f < (float)WW);
            bool vx1 = (x1f >= 0.f) && (x1f < (float)WW);
            bool vy0 = (y0f >= 0.f) && (y0f < (float)HH);
            bool vy1 = (y1f >= 0.f) && (y1f < (float)HH);
            float w00 = (vx0 && vy0) ? (1.f - fx) * (1.f - fy) : 0.f;
            float w01 = (vx1 && vy0) ? fx * (1.f - fy) : 0.f;
            float w10 = (vx0 && vy1) ? (1.f - fx) * fy : 0.f;
            float w11 = (vx1 && vy1) ? fx * fy : 0.f;

            const __half* base = srcT + (size_t)v * HW * CC;
            float d00 = tap_dot16(base + (size_t)(iy0 * WW + ix0) * CC, cf2);
            float d01 = tap_dot16(base + (size_t)(iy0 * WW + ix1) * CC, cf2);
            float d10 = tap_dot16(base + (size_t)(iy1 * WW + ix0) * CC, cf2);
            float d11 = tap_dot16(base + (size_t)(iy1 * WW + ix1) * CC, cf2);

            acc += w00 * d00 + w01 * d01 + w10 * d10 + w11 * d11;
        }
    }
    out[tid] = acc;
}

// ---------------------------------------------------------------------------
// Fallback (no workspace): original-layout fp32 gather.
// ---------------------------------------------------------------------------
__global__ __launch_bounds__(256) void cost_volume_fallback_kernel(
    const float* __restrict__ curF,   // (C,HW)
    const float* __restrict__ srcF,   // (V,C,HW)
    const float* __restrict__ extr,
    const float* __restrict__ Ks,
    const float* __restrict__ invK,
    const float* __restrict__ min_d,
    const float* __restrict__ max_d,
    float* __restrict__ out)
{
    __shared__ float P_s[VV * 12];
    {
        int t = threadIdx.x;
        if (t < VV * 12) {
            int v   = t / 12;
            int r   = (t % 12) / 4;
            int col = t % 4;
            float s = 0.f;
            #pragma unroll
            for (int k = 0; k < 4; ++k)
                s += Ks[v * 16 + r * 4 + k] * extr[v * 16 + k * 4 + col];
            P_s[t] = s;
        }
    }
    __syncthreads();

    int tid = blockIdx.x * blockDim.x + threadIdx.x;
    if (tid >= DD * HW) return;
    int d  = tid / HW;
    int hw = tid - d * HW;
    int h  = hw / WW;
    int w  = hw - h * WW;

    float px = (float)w + 0.5f, py = (float)h + 0.5f;
    float rx = invK[0] * px + invK[1] * py + invK[2];
    float ry = invK[4] * px + invK[5] * py + invK[6];
    float rz = invK[8] * px + invK[9] * py + invK[10];

    float inv_min = 1.f / min_d[0];
    float inv_max = 1.f / max_d[0];
    float depth   = 1.f / (inv_min + (inv_max - inv_min) * ((float)d / (float)(DD - 1)));

    float cf[CC];
    #pragma unroll
    for (int c = 0; c < CC; ++c) cf[c] = curF[c * HW + hw];

    float acc = 0.f;
    #pragma unroll
    for (int v = 0; v < VV; ++v) {
        const float* P = &P_s[v * 12];
        float cx = depth * (P[0] * rx + P[1] * ry + P[2]  * rz) + P[3];
        float cy = depth * (P[4] * rx + P[5] * ry + P[6]  * rz) + P[7];
        float cz = depth * (P[8] * rx + P[9] * ry + P[10] * rz) + P[11];
        if (cz > 0.f) {
            float iz = 1.f / (cz + EPSF);
            float x = cx * iz - 0.5f;
            float y = cy * iz - 0.5f;
            float x0f = floorf(x), y0f = floorf(y);
            float fx = x - x0f, fy = y - y0f;
            float x1f = x0f + 1.f, y1f = y0f + 1.f;
            int ix0 = (int)fminf(fmaxf(x0f, 0.f), (float)(WW - 1));
            int ix1 = (int)fminf(fmaxf(x1f, 0.f), (float)(WW - 1));
            int iy0 = (int)fminf(fmaxf(y0f, 0.f), (float)(HH - 1));
            int iy1 = (int)fminf(fmaxf(y1f, 0.f), (float)(HH - 1));
            bool vx0 = (x0f >= 0.f) && (x0f < (float)WW);
            bool vx1 = (x1f >= 0.f) && (x1f < (float)WW);
            bool vy0 = (y0f >= 0.f) && (y0f < (float)HH);
            bool vy1 = (y1f >= 0.f) && (y1f < (float)HH);
            float w00 = (vx0 && vy0) ? (1.f - fx) * (1.f - fy) : 0.f;
            float w01 = (vx1 && vy0) ? fx * (1.f - fy) : 0.f;
            float w10 = (vx0 && vy1) ? (1.f - fx) * fy : 0.f;
            float w11 = (vx1 && vy1) ? fx * fy : 0.f;

            float d00 = 0.f, d01 = 0.f, d10 = 0.f, d11 = 0.f;
            int b = v * CC * HW;
            int i00 = iy0 * WW + ix0, i01 = iy0 * WW + ix1;
            int i10 = iy1 * WW + ix0, i11 = iy1 * WW + ix1;
            #pragma unroll
            for (int c = 0; c < CC; ++c) {
                const float* fc = srcF + b + c * HW;
                d00 += fc[i00] * cf[c];
                d01 += fc[i01] * cf[c];
                d10 += fc[i10] * cf[c];
                d11 += fc[i11] * cf[c];
            }
            acc += w00 * d00 + w01 * d01 + w10 * d10 + w11 * d11;
        }
    }
    out[tid] = acc;
}

extern "C" void kernel_launch(void* const* d_in, const int* in_sizes, int n_in,
                              void* d_out, int out_size, void* d_ws, size_t ws_size,
                              hipStream_t stream) {
    const float* cur  = (const float*)d_in[0];
    const float* src  = (const float*)d_in[1];
    const float* extr = (const float*)d_in[2];
    const float* Ks   = (const float*)d_in[3];
    const float* invK = (const float*)d_in[4];
    const float* mind = (const float*)d_in[5];
    const float* maxd = (const float*)d_in[6];
    float* out = (float*)d_out;

    const size_t need = (size_t)(VV * HW * CC + HW * CC) * sizeof(__half);
    const int n_out  = DD * HW;
    const int blocks = (n_out + 255) / 256;

    if (ws_size >= need) {
        __half* srcT = (__half*)d_ws;
        __half* curT = srcT + (size_t)VV * HW * CC;
        const int total = VV * HW + HW;
        cv_pack_kernel<<<(total + 255) / 256, 256, 0, stream>>>(src, cur, srcT, curT);
        cost_volume_f16_kernel<<<blocks, 256, 0, stream>>>(
            curT, srcT, extr, Ks, invK, mind, maxd, out);
    } else {
        cost_volume_fallback_kernel<<<blocks, 256, 0, stream>>>(
            cur, src, extr, Ks, invK, mind, maxd, out);
    }
}